// Round 6
// baseline (821.189 us; speedup 1.0000x reference)
//
#include <hip/hip_runtime.h>
#include <math.h>

// ROUND 6: decisive in-graph timing decomposition. Kernels are byte-identical
// to round 5; phase1+phase2 are each launched TWICE (idempotent, deterministic)
// so that  dur_R6 - dur_R5 = t(phase1) + t(phase2)  measured inside the graph,
// independent of any assumption about the harness poison-fill's in-graph cost.

namespace {
constexpr int B    = 8;
constexpr int NCAM = 6;
constexpr int H    = 64;
constexpr int W    = 224;
constexpr int NW   = NCAM * W;            // 1344
constexpr int NPF  = 256;
constexpr int WP4  = NW / 4;              // 336
constexpr int NPIX = B * H * NW;          // 688,128 pixels
constexpr int PLANE  = H * NW;            // 86,016 floats per (b,c) plane
constexpr int PLANE4 = PLANE / 4;         // 21,504 float4 per plane (=336*64)
constexpr long long POS_ELEMS = (long long)B * NPF * (long long)PLANE; // 176,160,768
constexpr int N4 = (int)(POS_ELEMS / 4);  // 44,040,192 float4 chunks
constexpr int GRID2 = 2048;
constexpr int BLK2  = 256;
constexpr int ITERS = N4 / (GRID2 * BLK2);    // 84, exact
static_assert((long long)ITERS * GRID2 * BLK2 == (long long)N4, "exact sweep");
static_assert(PLANE4 % 64 == 0, "waves never straddle planes");
constexpr float C1     = 0.2076205059304498f;   // log2(10000)/64
constexpr float INV2PI = 0.15915494309189535f;  // 1/(2*pi)

typedef float f32x4 __attribute__((ext_vector_type(4)));
}

__device__ __forceinline__ void inv3(const float m[9], float o[9]) {
  float a = m[0], b = m[1], c = m[2];
  float d = m[3], e = m[4], f = m[5];
  float g = m[6], h = m[7], i = m[8];
  float A  =  e * i - f * h;
  float Bm = -(d * i - f * g);
  float C  =  d * h - e * g;
  float det = a * A + b * Bm + c * C;
  float r = 1.0f / det;
  o[0] = A * r;  o[1] = -(b * i - c * h) * r; o[2] =  (b * f - c * e) * r;
  o[3] = Bm * r; o[4] =  (a * i - c * g) * r; o[5] = -(a * f - c * d) * r;
  o[6] = C * r;  o[7] = -(a * h - b * g) * r; o[8] =  (a * e - b * d) * r;
}

__device__ __forceinline__ void mm3(const float* a, const float* bm, float* o) {
#pragma unroll
  for (int i = 0; i < 3; ++i)
#pragma unroll
    for (int j = 0; j < 3; ++j)
      o[i * 3 + j] = fmaf(a[i * 3 + 0], bm[0 * 3 + j],
                     fmaf(a[i * 3 + 1], bm[1 * 3 + j],
                          a[i * 3 + 2] * bm[2 * 3 + j]));
}

// ---- Phase 1: per-pixel geometry -> ws {X, Y, V planes} + valid out tail ----
__global__ __launch_bounds__(256) void ipm_coords_kernel(
    const float* __restrict__ ext, const float* __restrict__ intr,
    const float* __restrict__ ida, const int* __restrict__ do_flip,
    float* __restrict__ ws, float* __restrict__ out, int write_valid) {
  const int t   = blockIdx.x * blockDim.x + threadIdx.x;   // 0..172031
  const int wp4 = t % WP4;
  const int bh  = t / WP4;
  const int h   = bh % H;
  const int b   = bh / H;
  if (b >= B) return;
  const int wp0 = wp4 * 4;             // 4 consecutive px, one camera (224%4==0)
  const int cam = wp0 / W;

  const int mi = b * NCAM + cam;
  const float* E  = ext  + mi * 16;
  const float* Km = intr + mi * 9;
  const float* Am = ida  + mi * 9;

  float R[9] = {E[0], E[1], E[2], E[4], E[5], E[6], E[8], E[9], E[10]};
  const float tz = E[11];              // extrinsic[2][3]
  float K[9], A[9];
#pragma unroll
  for (int i = 0; i < 9; ++i) { K[i] = Km[i]; A[i] = Am[i]; }

  float Ki[9], Ai[9], M[9], RM[9];
  inv3(K, Ki);
  inv3(A, Ai);
  mm3(Ki, Ai, M);                      // K^-1 @ ida^-1
  mm3(R, M, RM);                       // R @ (K^-1 @ ida^-1)

  const float yp   = (float)h * (511.0f / 63.0f);
  const int   flip = *do_flip;

  float X[4], Y[4], V[4];
#pragma unroll
  for (int p = 0; p < 4; ++p) {
    const int w = wp0 + p - cam * W;
    const float xp = (float)w * (895.0f / 223.0f);
    float wx = fmaf(RM[0], xp, fmaf(RM[1], yp, RM[2]));
    float wy = fmaf(RM[3], xp, fmaf(RM[4], yp, RM[5]));
    float wz = fmaf(RM[6], xp, fmaf(RM[7], yp, RM[8]));
    float norm = fmaxf(sqrtf(wx * wx + wy * wy + wz * wz), 1e-12f);
    const float depth = -tz / (wz / norm);
    const bool valid  = depth > 0.0f;
    float Xp = (wx / norm) * depth;
    float Yp = (wy / norm) * depth;
    if (flip) Yp = -Yp;
    X[p] = valid ? Xp : 0.0f;          // masked px carry exactly +0
    Y[p] = valid ? Yp : 0.0f;
    V[p] = valid ? 1.0f : 0.0f;
  }

  const size_t o = (size_t)bh * NW + wp0;
  *(float4*)(ws + o)            = make_float4(X[0], X[1], X[2], X[3]);
  *(float4*)(ws + NPIX + o)     = make_float4(Y[0], Y[1], Y[2], Y[3]);
  *(float4*)(ws + 2 * NPIX + o) = make_float4(V[0], V[1], V[2], V[3]);
  if (write_valid)
    *(float4*)(out + POS_ELEMS + o) = make_float4(V[0], V[1], V[2], V[3]);
}

// ---- Phase 2: fill-shaped linear sweep over out; nt float4 stores ----
__global__ __launch_bounds__(256) void ipm_encode_kernel(
    const float* __restrict__ ws, float* __restrict__ out) {
  const int tid = blockIdx.x * BLK2 + threadIdx.x;

  for (int it = 0; it < ITERS; ++it) {
    const int chunk = it * (GRID2 * BLK2) + tid;   // linear float4 index in out
    const int p = chunk / PLANE4;                  // plane id — wave-uniform
    const int i = chunk - p * PLANE4;              // float4 index inside plane
    const int b = p >> 8;
    const int c = p & 255;
    const bool isX   = c >= 128;                   // c<128: py(Y); c>=128: px(X)
    const int  k     = (c & 127) >> 1;
    const bool isCos = (c & 1) != 0;

    const float inv_t = exp2f(-(float)k * C1);     // 1/10000^(k/64)
    const float ck    = inv_t * INV2PI;

    const f32x4 v = *(const f32x4*)(ws + (isX ? 0 : NPIX) +
                                    (size_t)b * PLANE + 4 * (size_t)i);
    const float am = fmaxf(fmaxf(fabsf(v.x), fabsf(v.y)),
                           fmaxf(fabsf(v.z), fabsf(v.w)));
    f32x4 r;
    if (__builtin_expect(!__any(am * inv_t > 800.0f), 1)) {
      // |arg| <= 800 rad -> |rev| <= 127.3, inside v_sin/v_cos +-256-rev
      // domain; error <= ~2e-4. Wave-uniform branches (one plane per wave).
      if (isCos) {
        r.x = __builtin_amdgcn_cosf(v.x * ck);
        r.y = __builtin_amdgcn_cosf(v.y * ck);
        r.z = __builtin_amdgcn_cosf(v.z * ck);
        r.w = __builtin_amdgcn_cosf(v.w * ck);
      } else {
        r.x = __builtin_amdgcn_sinf(v.x * ck);     // sin(+0)=+0: self-masking
        r.y = __builtin_amdgcn_sinf(v.y * ck);
        r.z = __builtin_amdgcn_sinf(v.z * ck);
        r.w = __builtin_amdgcn_sinf(v.w * ck);
      }
    } else {
      // Exact libm path (full range reduction) for huge-argument waves.
      const float tk = exp2f((float)k * C1);
      if (isCos) {
        r.x = cosf(v.x / tk); r.y = cosf(v.y / tk);
        r.z = cosf(v.z / tk); r.w = cosf(v.w / tk);
      } else {
        r.x = sinf(v.x / tk); r.y = sinf(v.y / tk);
        r.z = sinf(v.z / tk); r.w = sinf(v.w / tk);
      }
    }
    if (isCos) {                      // cos(0)=1 must be masked; sin(+0) ok
      const f32x4 m = *(const f32x4*)(ws + 2 * NPIX +
                                      (size_t)b * PLANE + 4 * (size_t)i);
      r.x *= m.x; r.y *= m.y; r.z *= m.z; r.w *= m.w;
    }
    __builtin_nontemporal_store(r, (f32x4*)(out + 4 * (size_t)chunk));
  }
}

extern "C" void kernel_launch(void* const* d_in, const int* in_sizes, int n_in,
                              void* d_out, int out_size, void* d_ws, size_t ws_size,
                              hipStream_t stream) {
  const float* ext  = (const float*)d_in[0];
  const float* intr = (const float*)d_in[1];
  const float* ida  = (const float*)d_in[2];
  const int*   flip = (const int*)d_in[3];
  float* out = (float*)d_out;
  float* ws  = (float*)d_ws;

  const int write_valid = ((long long)out_size > POS_ELEMS) ? 1 : 0;
  const int grid1 = (B * H * WP4 + 255) / 256;   // 672

  // Pass A (the real work)
  ipm_coords_kernel<<<grid1, 256, 0, stream>>>(ext, intr, ida, flip, ws, out,
                                               write_valid);
  ipm_encode_kernel<<<GRID2, BLK2, 0, stream>>>(ws, out);

  // Pass B: identical, idempotent re-run. Adds exactly t(p1)+t(p2) to the
  // graph; dur_R6 - dur_R5 isolates our kernels' true in-graph cost.
  ipm_coords_kernel<<<grid1, 256, 0, stream>>>(ext, intr, ida, flip, ws, out,
                                               write_valid);
  ipm_encode_kernel<<<GRID2, BLK2, 0, stream>>>(ws, out);
}

// Round 7
// 686.152 us; speedup vs baseline: 1.1968x; 1.1968x over previous
//
#include <hip/hip_runtime.h>
#include <math.h>

// ROUND 7 (revert of R6 diagnostic): single-pass R5 kernel. R6's in-graph
// decomposition measured t(phase1)+t(phase2) = 129 us vs a ~114 us HBM
// write floor (707 MB @ 6.3 TB/s achievable) — ~90% of the copy ceiling.
// The remaining ~563 us of dur_us is the harness's 0xAA poison fill
// (2.83 GB in-graph) + fixed overheads, not addressable from kernel code.

namespace {
constexpr int B    = 8;
constexpr int NCAM = 6;
constexpr int H    = 64;
constexpr int W    = 224;
constexpr int NW   = NCAM * W;            // 1344
constexpr int NPF  = 256;
constexpr int WP4  = NW / 4;              // 336
constexpr int NPIX = B * H * NW;          // 688,128 pixels
constexpr int PLANE  = H * NW;            // 86,016 floats per (b,c) plane
constexpr int PLANE4 = PLANE / 4;         // 21,504 float4 per plane (=336*64)
constexpr long long POS_ELEMS = (long long)B * NPF * (long long)PLANE; // 176,160,768
constexpr int N4 = (int)(POS_ELEMS / 4);  // 44,040,192 float4 chunks
constexpr int GRID2 = 2048;
constexpr int BLK2  = 256;
constexpr int ITERS = N4 / (GRID2 * BLK2);    // 84, exact
static_assert((long long)ITERS * GRID2 * BLK2 == (long long)N4, "exact sweep");
static_assert(PLANE4 % 64 == 0, "waves never straddle planes");
constexpr float C1     = 0.2076205059304498f;   // log2(10000)/64
constexpr float INV2PI = 0.15915494309189535f;  // 1/(2*pi)

typedef float f32x4 __attribute__((ext_vector_type(4)));
}

__device__ __forceinline__ void inv3(const float m[9], float o[9]) {
  float a = m[0], b = m[1], c = m[2];
  float d = m[3], e = m[4], f = m[5];
  float g = m[6], h = m[7], i = m[8];
  float A  =  e * i - f * h;
  float Bm = -(d * i - f * g);
  float C  =  d * h - e * g;
  float det = a * A + b * Bm + c * C;
  float r = 1.0f / det;
  o[0] = A * r;  o[1] = -(b * i - c * h) * r; o[2] =  (b * f - c * e) * r;
  o[3] = Bm * r; o[4] =  (a * i - c * g) * r; o[5] = -(a * f - c * d) * r;
  o[6] = C * r;  o[7] = -(a * h - b * g) * r; o[8] =  (a * e - b * d) * r;
}

__device__ __forceinline__ void mm3(const float* a, const float* bm, float* o) {
#pragma unroll
  for (int i = 0; i < 3; ++i)
#pragma unroll
    for (int j = 0; j < 3; ++j)
      o[i * 3 + j] = fmaf(a[i * 3 + 0], bm[0 * 3 + j],
                     fmaf(a[i * 3 + 1], bm[1 * 3 + j],
                          a[i * 3 + 2] * bm[2 * 3 + j]));
}

// ---- Phase 1: per-pixel geometry -> ws {X, Y, V planes} + valid out tail ----
__global__ __launch_bounds__(256) void ipm_coords_kernel(
    const float* __restrict__ ext, const float* __restrict__ intr,
    const float* __restrict__ ida, const int* __restrict__ do_flip,
    float* __restrict__ ws, float* __restrict__ out, int write_valid) {
  const int t   = blockIdx.x * blockDim.x + threadIdx.x;   // 0..172031
  const int wp4 = t % WP4;
  const int bh  = t / WP4;
  const int h   = bh % H;
  const int b   = bh / H;
  if (b >= B) return;
  const int wp0 = wp4 * 4;             // 4 consecutive px, one camera (224%4==0)
  const int cam = wp0 / W;

  const int mi = b * NCAM + cam;
  const float* E  = ext  + mi * 16;
  const float* Km = intr + mi * 9;
  const float* Am = ida  + mi * 9;

  float R[9] = {E[0], E[1], E[2], E[4], E[5], E[6], E[8], E[9], E[10]};
  const float tz = E[11];              // extrinsic[2][3]
  float K[9], A[9];
#pragma unroll
  for (int i = 0; i < 9; ++i) { K[i] = Km[i]; A[i] = Am[i]; }

  float Ki[9], Ai[9], M[9], RM[9];
  inv3(K, Ki);
  inv3(A, Ai);
  mm3(Ki, Ai, M);                      // K^-1 @ ida^-1
  mm3(R, M, RM);                       // R @ (K^-1 @ ida^-1)

  const float yp   = (float)h * (511.0f / 63.0f);
  const int   flip = *do_flip;

  float X[4], Y[4], V[4];
#pragma unroll
  for (int p = 0; p < 4; ++p) {
    const int w = wp0 + p - cam * W;
    const float xp = (float)w * (895.0f / 223.0f);
    float wx = fmaf(RM[0], xp, fmaf(RM[1], yp, RM[2]));
    float wy = fmaf(RM[3], xp, fmaf(RM[4], yp, RM[5]));
    float wz = fmaf(RM[6], xp, fmaf(RM[7], yp, RM[8]));
    float norm = fmaxf(sqrtf(wx * wx + wy * wy + wz * wz), 1e-12f);
    const float depth = -tz / (wz / norm);
    const bool valid  = depth > 0.0f;
    float Xp = (wx / norm) * depth;
    float Yp = (wy / norm) * depth;
    if (flip) Yp = -Yp;
    X[p] = valid ? Xp : 0.0f;          // masked px carry exactly +0
    Y[p] = valid ? Yp : 0.0f;
    V[p] = valid ? 1.0f : 0.0f;
  }

  const size_t o = (size_t)bh * NW + wp0;
  *(float4*)(ws + o)            = make_float4(X[0], X[1], X[2], X[3]);
  *(float4*)(ws + NPIX + o)     = make_float4(Y[0], Y[1], Y[2], Y[3]);
  *(float4*)(ws + 2 * NPIX + o) = make_float4(V[0], V[1], V[2], V[3]);
  if (write_valid)
    *(float4*)(out + POS_ELEMS + o) = make_float4(V[0], V[1], V[2], V[3]);
}

// ---- Phase 2: fill-shaped linear sweep over out; nt float4 stores ----
__global__ __launch_bounds__(256) void ipm_encode_kernel(
    const float* __restrict__ ws, float* __restrict__ out) {
  const int tid = blockIdx.x * BLK2 + threadIdx.x;

  for (int it = 0; it < ITERS; ++it) {
    const int chunk = it * (GRID2 * BLK2) + tid;   // linear float4 index in out
    const int p = chunk / PLANE4;                  // plane id — wave-uniform
    const int i = chunk - p * PLANE4;              // float4 index inside plane
    const int b = p >> 8;
    const int c = p & 255;
    const bool isX   = c >= 128;                   // c<128: py(Y); c>=128: px(X)
    const int  k     = (c & 127) >> 1;
    const bool isCos = (c & 1) != 0;

    const float inv_t = exp2f(-(float)k * C1);     // 1/10000^(k/64)
    const float ck    = inv_t * INV2PI;

    const f32x4 v = *(const f32x4*)(ws + (isX ? 0 : NPIX) +
                                    (size_t)b * PLANE + 4 * (size_t)i);
    const float am = fmaxf(fmaxf(fabsf(v.x), fabsf(v.y)),
                           fmaxf(fabsf(v.z), fabsf(v.w)));
    f32x4 r;
    if (__builtin_expect(!__any(am * inv_t > 800.0f), 1)) {
      // |arg| <= 800 rad -> |rev| <= 127.3, inside v_sin/v_cos +-256-rev
      // domain; error <= ~2e-4. Wave-uniform branches (one plane per wave).
      if (isCos) {
        r.x = __builtin_amdgcn_cosf(v.x * ck);
        r.y = __builtin_amdgcn_cosf(v.y * ck);
        r.z = __builtin_amdgcn_cosf(v.z * ck);
        r.w = __builtin_amdgcn_cosf(v.w * ck);
      } else {
        r.x = __builtin_amdgcn_sinf(v.x * ck);     // sin(+0)=+0: self-masking
        r.y = __builtin_amdgcn_sinf(v.y * ck);
        r.z = __builtin_amdgcn_sinf(v.z * ck);
        r.w = __builtin_amdgcn_sinf(v.w * ck);
      }
    } else {
      // Exact libm path (full range reduction) for huge-argument waves.
      const float tk = exp2f((float)k * C1);
      if (isCos) {
        r.x = cosf(v.x / tk); r.y = cosf(v.y / tk);
        r.z = cosf(v.z / tk); r.w = cosf(v.w / tk);
      } else {
        r.x = sinf(v.x / tk); r.y = sinf(v.y / tk);
        r.z = sinf(v.z / tk); r.w = sinf(v.w / tk);
      }
    }
    if (isCos) {                      // cos(0)=1 must be masked; sin(+0) ok
      const f32x4 m = *(const f32x4*)(ws + 2 * NPIX +
                                      (size_t)b * PLANE + 4 * (size_t)i);
      r.x *= m.x; r.y *= m.y; r.z *= m.z; r.w *= m.w;
    }
    __builtin_nontemporal_store(r, (f32x4*)(out + 4 * (size_t)chunk));
  }
}

extern "C" void kernel_launch(void* const* d_in, const int* in_sizes, int n_in,
                              void* d_out, int out_size, void* d_ws, size_t ws_size,
                              hipStream_t stream) {
  const float* ext  = (const float*)d_in[0];
  const float* intr = (const float*)d_in[1];
  const float* ida  = (const float*)d_in[2];
  const int*   flip = (const int*)d_in[3];
  float* out = (float*)d_out;
  float* ws  = (float*)d_ws;

  const int write_valid = ((long long)out_size > POS_ELEMS) ? 1 : 0;
  const int grid1 = (B * H * WP4 + 255) / 256;   // 672

  ipm_coords_kernel<<<grid1, 256, 0, stream>>>(ext, intr, ida, flip, ws, out,
                                               write_valid);
  ipm_encode_kernel<<<GRID2, BLK2, 0, stream>>>(ws, out);
}